// Round 14
// baseline (21519.447 us; speedup 1.0000x reference)
//
#include <hip/hip_runtime.h>
#include <math.h>

// NDDE forward-Euler DDE solve, D=768, N=8192 steps.
// x_{j+1} = x_j + dt * tanh(Wx x_j + Wy x_{j-10} + b),  dt = tau/10.
// Output: trajectory [D][N+1] fp32, out[i*(N+1)+k] = x_k[i].
//
// NUMERICS ARE FROZEN (passes at absmax 16.0 / thr 16.4): fp64-exact dots
// rounded per-dot to fp32; fp32 adds for z; correctly-rounded fp32 tanh via
// fp64; fp32 state update mul-then-add; per-row 32-lane x 24-col ownership,
// FMA order and shuffle reduction tree IDENTICAL to rounds 5/11/13
// (14.25 ms best). Row->WG bookkeeping changed only.
//
// Round 14 topology: 64 WGs x 384 thr (6 waves, 12 rows/WG, ALL waves
// compute — no pure pollers, the r6/r12 lesson). Changes vs r13:
//  1. Sweep = ONE global_load_dwordx4 sc0 sc1 per thread (packs 2t,2t+1;
//     384x2=768 exact). r12 validated the load; r12's regression was its
//     spinner waves, absent here.
//  2. 96->64 WGs: straggler max over fewer draws; device sweep requests
//     halve (49k->24.5k per round).
//  3. Speculative prefetch: plain volatile 16B read of the same packs at
//     loop top; compiler waits at first use (after y-dot) -> behind-schedule
//     WGs detect with zero added RT. Tag==j gates each pack's value within
//     the same line snapshot, so stale L1/L2 copies can only fail (harmless)
//     never falsely pass. Coherent sc0sc1 sweep loop + 8B-atomic fallback
//     (no-hang) unchanged.
//
// Encoded lessons: no fences (r3), no RMWs (r7), no extra detect hop (r9),
// no setprio on spinners (r6), no replication (r8), no pure-poller waves
// (r6/r12), VGPR must fit weights (r4/r10), LDS stride 33 (r13).

#define DD 768
#define NSTEPS 8192
#define NWG 64
#define NT 384
#define ROWS_PER_WG 12
#define COLS_PER_LANE 24
#define RING 16
#define LSTRIDE 33
#define LSLOT (COLS_PER_LANE * LSTRIDE)   // 792 words per history slot

#define RING_OFF 0   // RING * DD * 8B packs in d_ws

typedef __attribute__((ext_vector_type(4))) unsigned int u32x4;

__device__ __forceinline__ unsigned long long ld_tag(const unsigned long long* p) {
    return __hip_atomic_load(p, __ATOMIC_RELAXED, __HIP_MEMORY_SCOPE_AGENT);
}

// One coherent 16B load of two (value|tag) packs: x=val0 y=tag0 z=val1 w=tag1.
// sc0 sc1 -> serviced at the device coherence point (validated r12/r13).
__device__ __forceinline__ u32x4 ld_pair(const unsigned long long* p) {
    u32x4 v;
    asm volatile("global_load_dwordx4 %0, %1, off sc0 sc1\n\t"
                 "s_waitcnt vmcnt(0)"
                 : "=v"(v) : "v"(p) : "memory");
    return v;
}

__global__ __launch_bounds__(NT, 1)
void ndde_kernel(const float* __restrict__ x0,
                 const float* __restrict__ tau,
                 const float* __restrict__ Wx,
                 const float* __restrict__ Wy,
                 const float* __restrict__ b,
                 float* __restrict__ out,
                 unsigned long long* __restrict__ ring)
{
    // Padded transposed f32 LDS history (r13): column i at
    // hist[slot*LSLOT + (i%24)*33 + i/24]. Dot-read bank=(k+c)%32 —
    // conflict-free; broadcast writes ~6-way (vs 24-way unpadded).
    __shared__ float hist[RING * LSLOT];          // 50.7 KB

    const int tid = threadIdx.x;
    const int g   = blockIdx.x;
    const int r   = tid >> 5;            // local row 0..11
    const int c   = tid & 31;            // lane-within-row 0..31
    const int row = g * ROWS_PER_WG + r;
    const int cb  = c * COLS_PER_LANE;

    const float dtf = tau[0] / 10.0f;

    // ---- stage weights as f32 (cvt to f64 at use, exact) ----
    float wxf[COLS_PER_LANE], wyf[COLS_PER_LANE];
    {
        const float* px = Wx + row * DD + cb;
        const float* py = Wy + row * DD + cb;
        #pragma unroll
        for (int i = 0; i < COLS_PER_LANE / 4; ++i) {
            float4 a = *(const float4*)(px + 4 * i);
            wxf[4*i+0] = a.x; wxf[4*i+1] = a.y; wxf[4*i+2] = a.z; wxf[4*i+3] = a.w;
            float4 d2 = *(const float4*)(py + 4 * i);
            wyf[4*i+0] = d2.x; wyf[4*i+1] = d2.y; wyf[4*i+2] = d2.z; wyf[4*i+3] = d2.w;
        }
    }
    #pragma unroll
    for (int i = 0; i < COLS_PER_LANE; ++i) {
        asm volatile("" : "+v"(wxf[i]));
        asm volatile("" : "+v"(wyf[i]));
    }

    const float brow = b[row];
    float xrow = x0[row];                // lane c==0 carries x_j[row]
    if (c == 0) out[row * (NSTEPS + 1) + 0] = xrow;

    for (int j = 0; j < NSTEPS; ++j) {
        const unsigned long long* base = ring + (j & (RING - 1)) * DD;
        const unsigned long long* p4   = base + 2 * tid;   // packs 2t, 2t+1

        // ---- speculative prefetch of this thread's 2 packs: issued here,
        // compiler's waitcnt lands at first use (after the y-dot) ----
        u32x4 spec;
        if (j >= 1) {
            spec = *(const volatile u32x4*)p4;
        }

        // ---- delayed half: y = x_{j-10} from LDS history (frozen math) ----
        double dy0 = 0.0, dy1 = 0.0;
        if (j <= 10) {
            const float* ys = x0 + cb;
            #pragma unroll
            for (int i = 0; i < COLS_PER_LANE / 4; ++i) {
                float4 v = *(const float4*)(ys + 4 * i);
                dy0 = fma((double)wyf[4*i+0], (double)v.x, dy0);
                dy1 = fma((double)wyf[4*i+1], (double)v.y, dy1);
                dy0 = fma((double)wyf[4*i+2], (double)v.z, dy0);
                dy1 = fma((double)wyf[4*i+3], (double)v.w, dy1);
            }
        } else {
            const float* hs = hist + ((j - 10) & (RING - 1)) * LSLOT;
            #pragma unroll
            for (int k = 0; k < COLS_PER_LANE; k += 4) {
                float v0 = hs[(k+0)*LSTRIDE + c];
                float v1 = hs[(k+1)*LSTRIDE + c];
                float v2 = hs[(k+2)*LSTRIDE + c];
                float v3 = hs[(k+3)*LSTRIDE + c];
                dy0 = fma((double)wyf[k+0], (double)v0, dy0);
                dy1 = fma((double)wyf[k+1], (double)v1, dy1);
                dy0 = fma((double)wyf[k+2], (double)v2, dy0);
                dy1 = fma((double)wyf[k+3], (double)v3, dy1);
            }
        }
        double doty = dy0 + dy1;
        #pragma unroll
        for (int off = 1; off < 32; off <<= 1)
            doty += __shfl_xor(doty, off);

        // ---- detect + fetch: speculative check first (zero added RT),
        // else coherent 1-request sweeps; broadcast to LDS; barrier ----
        if (j >= 1) {
            const unsigned tgt = (unsigned)j;
            unsigned v0, v1;
            bool got;
            {
                bool ok = (spec.y == tgt) & (spec.w == tgt);
                got = __all(ok);
                v0 = spec.x; v1 = spec.z;
            }
            int tries = 0;
            while (!got) {
                bool ok;
                if (tries < 2048) {
                    u32x4 q = ld_pair(p4);
                    v0 = q.x; v1 = q.z;
                    ok = (q.y == tgt) & (q.w == tgt);
                } else {               // proven fallback (no-hang)
                    unsigned long long q0 = ld_tag(p4 + 0);
                    unsigned long long q1 = ld_tag(p4 + 1);
                    v0 = (unsigned)q0; v1 = (unsigned)q1;
                    ok = ((unsigned)(q0 >> 32) == tgt) &
                         ((unsigned)(q1 >> 32) == tgt);
                }
                got = __all(ok);
                ++tries;
            }
            float* hsw = hist + (j & (RING - 1)) * LSLOT;
            const int iA = 2 * tid, iB = 2 * tid + 1;
            hsw[(iA % 24) * LSTRIDE + (iA / 24)] = __uint_as_float(v0);
            hsw[(iB % 24) * LSTRIDE + (iB / 24)] = __uint_as_float(v1);
            __syncthreads();
        }

        // ---- live half: Wx · x_j from LDS (frozen math) ----
        double dx0 = 0.0, dx1 = 0.0;
        if (j == 0) {
            const float* xs = x0 + cb;
            #pragma unroll
            for (int i = 0; i < COLS_PER_LANE / 4; ++i) {
                float4 v = *(const float4*)(xs + 4 * i);
                dx0 = fma((double)wxf[4*i+0], (double)v.x, dx0);
                dx1 = fma((double)wxf[4*i+1], (double)v.y, dx1);
                dx0 = fma((double)wxf[4*i+2], (double)v.z, dx0);
                dx1 = fma((double)wxf[4*i+3], (double)v.w, dx1);
            }
        } else {
            const float* hs = hist + (j & (RING - 1)) * LSLOT;
            #pragma unroll
            for (int k = 0; k < COLS_PER_LANE; k += 4) {
                float v0 = hs[(k+0)*LSTRIDE + c];
                float v1 = hs[(k+1)*LSTRIDE + c];
                float v2 = hs[(k+2)*LSTRIDE + c];
                float v3 = hs[(k+3)*LSTRIDE + c];
                dx0 = fma((double)wxf[k+0], (double)v0, dx0);
                dx1 = fma((double)wxf[k+1], (double)v1, dx1);
                dx0 = fma((double)wxf[k+2], (double)v2, dx0);
                dx1 = fma((double)wxf[k+3], (double)v3, dx1);
            }
        }
        double dotx = dx0 + dx1;
        #pragma unroll
        for (int off = 1; off < 32; off <<= 1)
            dotx += __shfl_xor(dotx, off);

        if (c == 0) {
            // z = (dot1_f32 + dot2_f32) + b, all fp32 adds (frozen)
            float z = __fadd_rn(__fadd_rn((float)dotx, (float)doty), brow);
            float th;
            float az = fabsf(z);
            if (az < 9.3f) th = (float)tanh((double)z);  // correctly-rounded
            else           th = (z > 0.0f) ? 1.0f : -1.0f;
            // x_next = x + dt*F, fp32 mul then fp32 add (frozen)
            xrow = __fadd_rn(xrow, __fmul_rn(dtf, th));

            // publish: (value|tag) in one relaxed agent-scope 8B store
            unsigned long long pack =
                ((unsigned long long)(unsigned)(j + 1) << 32) |
                (unsigned long long)__float_as_uint(xrow);
            __hip_atomic_store(&ring[((j + 1) & (RING - 1)) * DD + row], pack,
                               __ATOMIC_RELAXED, __HIP_MEMORY_SCOPE_AGENT);

            // trajectory write — off the critical path
            out[row * (NSTEPS + 1) + (j + 1)] = xrow;
        }
    }
}

extern "C" void kernel_launch(void* const* d_in, const int* in_sizes, int n_in,
                              void* d_out, int out_size, void* d_ws, size_t ws_size,
                              hipStream_t stream) {
    (void)in_sizes; (void)n_in; (void)out_size; (void)ws_size;

    const float* x0  = (const float*)d_in[0];
    const float* tau = (const float*)d_in[1];
    const float* Wx  = (const float*)d_in[2];
    const float* Wy  = (const float*)d_in[3];
    const float* b   = (const float*)d_in[4];
    float* out = (float*)d_out;

    unsigned long long* ring = (unsigned long long*)((char*)d_ws + RING_OFF);

    // No memset needed: strict tag==j matching rejects 0xAA poison and stale
    // replay tags (slot j%16 is freshly rewritten long before step j needs it).
    ndde_kernel<<<NWG, NT, 0, stream>>>(x0, tau, Wx, Wy, b, out, ring);
}

// Round 15
// 16137.111 us; speedup vs baseline: 1.3335x; 1.3335x over previous
//
#include <hip/hip_runtime.h>
#include <math.h>

// NDDE forward-Euler DDE solve, D=768, N=8192 steps.
// x_{j+1} = x_j + dt * tanh(Wx x_j + Wy x_{j-10} + b),  dt = tau/10.
// Output: trajectory [D][N+1] fp32, out[i*(N+1)+k] = x_k[i].
//
// NUMERICS ARE FROZEN (passes at absmax 16.0 / thr 16.4): fp64-exact dots
// rounded per-dot to fp32; fp32 adds for z; correctly-rounded fp32 tanh via
// fp64; fp32 state update mul-then-add; per-row 32-lane x 24-col ownership,
// FMA order and shuffle reduction tree IDENTICAL to rounds 5/11/13.
//
// Round 15 = round 14 MINUS the speculative prefetch (clean A/B). r14's
// FETCH_SIZE doubling (223->501 MB) identified the plain-cached volatile
// prefetch as the toxin: non-sc0 loads allocate stale ring lines in the
// local (non-coherent) XCD L2 -> never pass, pure thrash. Topology kept:
// 64 WGs x 384 thr (12 rows/WG, ALL 6 waves compute; no pure pollers).
// Sweep = ONE global_load_dwordx4 sc0 sc1 per thread (2 packs, 384x2=768
// exact cover) — single request, 1 RT, window-confined. 8B-atomic fallback
// (no-hang) retained. LDS stride 33 (r13).
//
// Encoded lessons: no fences (r3), no RMWs (r7), no extra detect hop (r9),
// no setprio on spinners (r6), no replication (r8), no pure-poller waves
// (r6/r12), no non-coherent speculative reads (r14), VGPR must fit weights
// (r4/r10).

#define DD 768
#define NSTEPS 8192
#define NWG 64
#define NT 384
#define ROWS_PER_WG 12
#define COLS_PER_LANE 24
#define RING 16
#define LSTRIDE 33
#define LSLOT (COLS_PER_LANE * LSTRIDE)   // 792 words per history slot

#define RING_OFF 0   // RING * DD * 8B packs in d_ws

typedef __attribute__((ext_vector_type(4))) unsigned int u32x4;

__device__ __forceinline__ unsigned long long ld_tag(const unsigned long long* p) {
    return __hip_atomic_load(p, __ATOMIC_RELAXED, __HIP_MEMORY_SCOPE_AGENT);
}

// One coherent 16B load of two (value|tag) packs: x=val0 y=tag0 z=val1 w=tag1.
// sc0 sc1 -> serviced at the device coherence point (validated r12/r13).
__device__ __forceinline__ u32x4 ld_pair(const unsigned long long* p) {
    u32x4 v;
    asm volatile("global_load_dwordx4 %0, %1, off sc0 sc1\n\t"
                 "s_waitcnt vmcnt(0)"
                 : "=v"(v) : "v"(p) : "memory");
    return v;
}

__global__ __launch_bounds__(NT, 1)
void ndde_kernel(const float* __restrict__ x0,
                 const float* __restrict__ tau,
                 const float* __restrict__ Wx,
                 const float* __restrict__ Wy,
                 const float* __restrict__ b,
                 float* __restrict__ out,
                 unsigned long long* __restrict__ ring)
{
    // Padded transposed f32 LDS history (r13): column i at
    // hist[slot*LSLOT + (i%24)*33 + i/24]. Dot-read bank=(k+c)%32 —
    // conflict-free; broadcast writes ~6-way (vs 24-way unpadded).
    __shared__ float hist[RING * LSLOT];          // 50.7 KB

    const int tid = threadIdx.x;
    const int g   = blockIdx.x;
    const int r   = tid >> 5;            // local row 0..11
    const int c   = tid & 31;            // lane-within-row 0..31
    const int row = g * ROWS_PER_WG + r;
    const int cb  = c * COLS_PER_LANE;

    const float dtf = tau[0] / 10.0f;

    // ---- stage weights as f32 (cvt to f64 at use, exact) ----
    float wxf[COLS_PER_LANE], wyf[COLS_PER_LANE];
    {
        const float* px = Wx + row * DD + cb;
        const float* py = Wy + row * DD + cb;
        #pragma unroll
        for (int i = 0; i < COLS_PER_LANE / 4; ++i) {
            float4 a = *(const float4*)(px + 4 * i);
            wxf[4*i+0] = a.x; wxf[4*i+1] = a.y; wxf[4*i+2] = a.z; wxf[4*i+3] = a.w;
            float4 d2 = *(const float4*)(py + 4 * i);
            wyf[4*i+0] = d2.x; wyf[4*i+1] = d2.y; wyf[4*i+2] = d2.z; wyf[4*i+3] = d2.w;
        }
    }
    #pragma unroll
    for (int i = 0; i < COLS_PER_LANE; ++i) {
        asm volatile("" : "+v"(wxf[i]));
        asm volatile("" : "+v"(wyf[i]));
    }

    const float brow = b[row];
    float xrow = x0[row];                // lane c==0 carries x_j[row]
    if (c == 0) out[row * (NSTEPS + 1) + 0] = xrow;

    for (int j = 0; j < NSTEPS; ++j) {
        // ---- delayed half: y = x_{j-10} from LDS history (frozen math) ----
        double dy0 = 0.0, dy1 = 0.0;
        if (j <= 10) {
            const float* ys = x0 + cb;
            #pragma unroll
            for (int i = 0; i < COLS_PER_LANE / 4; ++i) {
                float4 v = *(const float4*)(ys + 4 * i);
                dy0 = fma((double)wyf[4*i+0], (double)v.x, dy0);
                dy1 = fma((double)wyf[4*i+1], (double)v.y, dy1);
                dy0 = fma((double)wyf[4*i+2], (double)v.z, dy0);
                dy1 = fma((double)wyf[4*i+3], (double)v.w, dy1);
            }
        } else {
            const float* hs = hist + ((j - 10) & (RING - 1)) * LSLOT;
            #pragma unroll
            for (int k = 0; k < COLS_PER_LANE; k += 4) {
                float v0 = hs[(k+0)*LSTRIDE + c];
                float v1 = hs[(k+1)*LSTRIDE + c];
                float v2 = hs[(k+2)*LSTRIDE + c];
                float v3 = hs[(k+3)*LSTRIDE + c];
                dy0 = fma((double)wyf[k+0], (double)v0, dy0);
                dy1 = fma((double)wyf[k+1], (double)v1, dy1);
                dy0 = fma((double)wyf[k+2], (double)v2, dy0);
                dy1 = fma((double)wyf[k+3], (double)v3, dy1);
            }
        }
        double doty = dy0 + dy1;
        #pragma unroll
        for (int off = 1; off < 32; off <<= 1)
            doty += __shfl_xor(doty, off);

        // ---- ALL 6 waves: 1-request sweep (2 packs/thread, exact cover),
        // window-confined; broadcast to LDS; barrier ----
        if (j >= 1) {
            const unsigned tgt = (unsigned)j;
            const unsigned long long* p4 =
                ring + (j & (RING - 1)) * DD + 2 * tid;
            unsigned v0, v1;
            int tries = 0;
            for (;;) {
                bool ok;
                if (tries < 2048) {
                    u32x4 q = ld_pair(p4);
                    v0 = q.x; v1 = q.z;
                    ok = (q.y == tgt) & (q.w == tgt);
                } else {               // proven fallback (no-hang)
                    unsigned long long q0 = ld_tag(p4 + 0);
                    unsigned long long q1 = ld_tag(p4 + 1);
                    v0 = (unsigned)q0; v1 = (unsigned)q1;
                    ok = ((unsigned)(q0 >> 32) == tgt) &
                         ((unsigned)(q1 >> 32) == tgt);
                }
                if (__all(ok)) break;
                ++tries;
            }
            float* hsw = hist + (j & (RING - 1)) * LSLOT;
            const int iA = 2 * tid, iB = 2 * tid + 1;
            hsw[(iA % 24) * LSTRIDE + (iA / 24)] = __uint_as_float(v0);
            hsw[(iB % 24) * LSTRIDE + (iB / 24)] = __uint_as_float(v1);
            __syncthreads();
        }

        // ---- live half: Wx · x_j from LDS (frozen math) ----
        double dx0 = 0.0, dx1 = 0.0;
        if (j == 0) {
            const float* xs = x0 + cb;
            #pragma unroll
            for (int i = 0; i < COLS_PER_LANE / 4; ++i) {
                float4 v = *(const float4*)(xs + 4 * i);
                dx0 = fma((double)wxf[4*i+0], (double)v.x, dx0);
                dx1 = fma((double)wxf[4*i+1], (double)v.y, dx1);
                dx0 = fma((double)wxf[4*i+2], (double)v.z, dx0);
                dx1 = fma((double)wxf[4*i+3], (double)v.w, dx1);
            }
        } else {
            const float* hs = hist + (j & (RING - 1)) * LSLOT;
            #pragma unroll
            for (int k = 0; k < COLS_PER_LANE; k += 4) {
                float v0 = hs[(k+0)*LSTRIDE + c];
                float v1 = hs[(k+1)*LSTRIDE + c];
                float v2 = hs[(k+2)*LSTRIDE + c];
                float v3 = hs[(k+3)*LSTRIDE + c];
                dx0 = fma((double)wxf[k+0], (double)v0, dx0);
                dx1 = fma((double)wxf[k+1], (double)v1, dx1);
                dx0 = fma((double)wxf[k+2], (double)v2, dx0);
                dx1 = fma((double)wxf[k+3], (double)v3, dx1);
            }
        }
        double dotx = dx0 + dx1;
        #pragma unroll
        for (int off = 1; off < 32; off <<= 1)
            dotx += __shfl_xor(dotx, off);

        if (c == 0) {
            // z = (dot1_f32 + dot2_f32) + b, all fp32 adds (frozen)
            float z = __fadd_rn(__fadd_rn((float)dotx, (float)doty), brow);
            float th;
            float az = fabsf(z);
            if (az < 9.3f) th = (float)tanh((double)z);  // correctly-rounded
            else           th = (z > 0.0f) ? 1.0f : -1.0f;
            // x_next = x + dt*F, fp32 mul then fp32 add (frozen)
            xrow = __fadd_rn(xrow, __fmul_rn(dtf, th));

            // publish: (value|tag) in one relaxed agent-scope 8B store
            unsigned long long pack =
                ((unsigned long long)(unsigned)(j + 1) << 32) |
                (unsigned long long)__float_as_uint(xrow);
            __hip_atomic_store(&ring[((j + 1) & (RING - 1)) * DD + row], pack,
                               __ATOMIC_RELAXED, __HIP_MEMORY_SCOPE_AGENT);

            // trajectory write — off the critical path
            out[row * (NSTEPS + 1) + (j + 1)] = xrow;
        }
    }
}

extern "C" void kernel_launch(void* const* d_in, const int* in_sizes, int n_in,
                              void* d_out, int out_size, void* d_ws, size_t ws_size,
                              hipStream_t stream) {
    (void)in_sizes; (void)n_in; (void)out_size; (void)ws_size;

    const float* x0  = (const float*)d_in[0];
    const float* tau = (const float*)d_in[1];
    const float* Wx  = (const float*)d_in[2];
    const float* Wy  = (const float*)d_in[3];
    const float* b   = (const float*)d_in[4];
    float* out = (float*)d_out;

    unsigned long long* ring = (unsigned long long*)((char*)d_ws + RING_OFF);

    // No memset needed: strict tag==j matching rejects 0xAA poison and stale
    // replay tags (slot j%16 is freshly rewritten long before step j needs it).
    ndde_kernel<<<NWG, NT, 0, stream>>>(x0, tau, Wx, Wy, b, out, ring);
}